// Round 5
// baseline (186.121 us; speedup 1.0000x reference)
//
#include <hip/hip_runtime.h>
#include <stdint.h>
#include <stddef.h>

// BinarizeLinearWithFoldedBN on MI355X (gfx950).
// out[b,o] = dot(sign(x[b,:]), sign(w[o,:])) * scale[o] + bias[o]
//   scale = gamma/sqrt(var+eps), bias = beta - mean*scale (exact BN algebra)
// i8 (+1/-1) MFMA GEMM, 256x256 tile, 8 waves, 4-deep slab pipeline:
//   BK=64B slabs, 4 LDS buffers, prefetch distance 3, counted vmcnt(12),
//   compiler-managed counted lgkmcnt (no manual drains), 2 barriers/K-step.
// T1 XCD swizzle + T2 granule swizzle (verified 0 conflicts) + T5 setprio.

#define BN_EPS 1e-5f
typedef int v4i __attribute__((ext_vector_type(4)));

// ---------------- BN fold ----------------
__global__ void bn_prep_kernel(const float* __restrict__ g, const float* __restrict__ b,
                               const float* __restrict__ m, const float* __restrict__ v,
                               float* __restrict__ scale, float* __restrict__ bias, int n) {
  int i = blockIdx.x * blockDim.x + threadIdx.x;
  if (i >= n) return;
  float s = g[i] * rsqrtf(v[i] + BN_EPS);
  scale[i] = s;
  bias[i] = b[i] - m[i] * s;
}

// ---------------- pack f32 signs -> i8 +1/-1 (16 floats -> 16 bytes per thread) ----
__global__ __launch_bounds__(256) void pack_sign_i8_kernel(
    const uint4* __restrict__ in, uint4* __restrict__ outp, int n16) {
  int t = blockIdx.x * blockDim.x + threadIdx.x;
  if (t >= n16) return;
  const uint4* p = in + (size_t)t * 4;
  uint32_t w[4];
#pragma unroll
  for (int i = 0; i < 4; ++i) {
    uint4 u = p[i];
    uint32_t m = (((uint32_t)((int)u.x >> 31)) & 0xFEu)
               | ((((uint32_t)((int)u.y >> 31)) & 0xFEu) << 8)
               | ((((uint32_t)((int)u.z >> 31)) & 0xFEu) << 16)
               | ((((uint32_t)((int)u.w >> 31)) & 0xFEu) << 24);
    w[i] = 0x01010101u ^ m;
  }
  uint4 o; o.x = w[0]; o.y = w[1]; o.z = w[2]; o.w = w[3];
  outp[t] = o;
}

// ---------------- i8 MFMA GEMM: 256x256 tile, 8 waves, 4-deep slab pipeline ----------
// LDS (128 KiB): A slab buf q (q=0..3): q*16384          (256 rows x 64 B)
//                B slab buf q:          65536 + q*16384
// 16B-granule XOR swizzle (T2): LDS(row R, chunk C) = global granule C ^ ((R>>1)&3).
//   write side: linear gload_lds dest + pre-swizzled SOURCE granule;
//   read side: fragment chunk = (lane>>4) ^ ((ln15>>1)&3). (Round-4: 0 conflicts.)
// Per K-step (slab s, buf s&3): stage slab s+3 (4 gloads), vmcnt(12), barrier,
//   12 ds_read_b128 (A mh0/mh1 + B), 2x16 MFMA (setprio-bracketed), barrier.

#define BAR() asm volatile("s_barrier" ::: "memory")
#define WAITV(n) asm volatile("s_waitcnt vmcnt(" #n ")" ::: "memory")

__global__ __launch_bounds__(512, 2) void bgemm_i8_p4(
    const int8_t* __restrict__ A8, const int8_t* __restrict__ B8,
    const float* __restrict__ scale, const float* __restrict__ bias,
    float* __restrict__ out, int M, int N, int K) {
  __shared__ __align__(16) int8_t lds[131072];

  const int tid = threadIdx.x;
  const int lane = tid & 63;
  const int wid = tid >> 6;      // 0..7
  const int wm = wid >> 2;       // 0..1  (128-row band)
  const int wn = wid & 3;        // 0..3  (64-col band)

  // T1: bijective XCD swizzle (nwg % 8 == 0 here: 32*16 = 512)
  const int nbx = N >> 8;
  const int nwg = (M >> 8) * nbx;
  const int cpx = nwg >> 3;
  const int bid = (int)blockIdx.x;
  const int swz = (bid & 7) * cpx + (bid >> 3);
  const int row0 = (swz / nbx) << 8;
  const int col0 = (swz % nbx) << 8;

  const int ln15 = lane & 15;
  // T2 read-side swizzle: fragment k-chunk byte offset
  const int kcs = (((lane >> 4) ^ ((ln15 >> 1) & 3)) << 4);
  const int arow = wm * 128 + ln15;         // + mh*64 + m*16
  const int brow = wn * 64 + ln15;          // + n*16
  const int srow = wid * 16 + (lane >> 2);  // staging row (2nd inst adds 128)
  // T2 write-side: pre-swizzled SOURCE granule (dest row bits (lane>>3)&3)
  const int sch = (((lane & 3) ^ ((lane >> 3) & 3)) << 4);
  const int ldw = wid << 10;                // wave slot in 8KB half-slab

  const size_t rstr = (size_t)128 * K;
  const int8_t* aSt = A8 + (size_t)(row0 + srow) * K + sch;
  const int8_t* bSt = B8 + (size_t)(col0 + srow) * K + sch;

  v4i acc[8][4];
#pragma unroll
  for (int i = 0; i < 8; ++i)
#pragma unroll
    for (int n = 0; n < 4; ++n) { v4i z = {0, 0, 0, 0}; acc[i][n] = z; }

  v4i a[8], b[4];

  // stage slab s (64B of K starting at s*64) into buf s&3 : 4 global_load_lds
#define STAGE(s) do {                                                                 \
  const int bb_ = ((s) & 3) * 16384;                                                  \
  __builtin_amdgcn_global_load_lds(                                                   \
      (const __attribute__((address_space(1))) uint32_t*)(aSt + (size_t)(s) * 64),    \
      (__attribute__((address_space(3))) uint32_t*)(lds + bb_ + ldw), 16, 0, 0);      \
  __builtin_amdgcn_global_load_lds(                                                   \
      (const __attribute__((address_space(1))) uint32_t*)(aSt + rstr + (size_t)(s) * 64), \
      (__attribute__((address_space(3))) uint32_t*)(lds + bb_ + 8192 + ldw), 16, 0, 0); \
  __builtin_amdgcn_global_load_lds(                                                   \
      (const __attribute__((address_space(1))) uint32_t*)(bSt + (size_t)(s) * 64),    \
      (__attribute__((address_space(3))) uint32_t*)(lds + 65536 + bb_ + ldw), 16, 0, 0); \
  __builtin_amdgcn_global_load_lds(                                                   \
      (const __attribute__((address_space(1))) uint32_t*)(bSt + rstr + (size_t)(s) * 64), \
      (__attribute__((address_space(3))) uint32_t*)(lds + 65536 + bb_ + 8192 + ldw), 16, 0, 0); \
} while (0)

  // read all fragments + 2 MFMA clusters for slab in buf q
#define COMPUTE(q) do {                                                               \
  const int8_t* ap_ = lds + (q) * 16384 + arow * 64 + kcs;                            \
  const int8_t* bp_ = lds + 65536 + (q) * 16384 + brow * 64 + kcs;                    \
  _Pragma("unroll")                                                                   \
  for (int m_ = 0; m_ < 4; ++m_) {                                                    \
    a[m_]     = *(const v4i*)(ap_ + m_ * 1024);                                       \
    a[4 + m_] = *(const v4i*)(ap_ + 4096 + m_ * 1024);                                \
    b[m_]     = *(const v4i*)(bp_ + m_ * 1024);                                       \
  }                                                                                   \
  __builtin_amdgcn_s_setprio(1);                                                      \
  _Pragma("unroll")                                                                   \
  for (int n_ = 0; n_ < 4; ++n_)                                                      \
    _Pragma("unroll")                                                                 \
    for (int m_ = 0; m_ < 4; ++m_)                                                    \
      acc[m_][n_] = __builtin_amdgcn_mfma_i32_16x16x64_i8(a[m_], b[n_], acc[m_][n_], 0, 0, 0); \
  __builtin_amdgcn_s_setprio(0);                                                      \
  __builtin_amdgcn_s_setprio(1);                                                      \
  _Pragma("unroll")                                                                   \
  for (int n_ = 0; n_ < 4; ++n_)                                                      \
    _Pragma("unroll")                                                                 \
    for (int m_ = 0; m_ < 4; ++m_)                                                    \
      acc[4 + m_][n_] = __builtin_amdgcn_mfma_i32_16x16x64_i8(a[4 + m_], b[n_], acc[4 + m_][n_], 0, 0, 0); \
  __builtin_amdgcn_s_setprio(0);                                                      \
} while (0)

  const int NT = K >> 6;   // 64-byte K-steps

  // ---- prologue: prefetch slabs 0,1,2 (12 loads in flight)
  STAGE(0); STAGE(1); STAGE(2);

  // ---- main loop: compute slab t, stage slab t+3 (prefetch distance 3)
  for (int t = 0; t < NT - 3; ++t) {
    STAGE(t + 3);            // 16 loads in flight (t..t+3)
    WAITV(12);               // slab t's 4 loads retired (this wave)
    BAR();                   // ... for ALL waves -> slab t fully in LDS
    COMPUTE(t & 3);
    BAR();                   // all waves done reading buf t&3 -> next stage may reuse it
  }

  // ---- epilogue: drain 8 -> 4 -> 0
  WAITV(8);  BAR(); COMPUTE((NT - 3) & 3); BAR();
  WAITV(4);  BAR(); COMPUTE((NT - 2) & 3); BAR();
  WAITV(0);  BAR(); COMPUTE((NT - 1) & 3);

  // ---- epilogue: C/D layout col = lane&15, row = (lane>>4)*4 + reg; acc[i] <-> rows wm*128+i*16
  const int cw = col0 + wn * 64;
  float scv[4], biv[4];
#pragma unroll
  for (int n = 0; n < 4; ++n) {
    int c = cw + n * 16 + ln15;
    scv[n] = scale[c];
    biv[n] = bias[c];
  }
#pragma unroll
  for (int i = 0; i < 8; ++i) {
    const int r0 = row0 + wm * 128 + i * 16 + ((lane >> 4) << 2);
#pragma unroll
    for (int reg = 0; reg < 4; ++reg) {
      float* orow = out + (size_t)(r0 + reg) * N;
#pragma unroll
      for (int n = 0; n < 4; ++n)
        orow[cw + n * 16 + ln15] = fmaf((float)acc[i][n][reg], scv[n], biv[n]);
    }
  }

#undef STAGE
#undef COMPUTE
}

// ======================= launch =======================
extern "C" void kernel_launch(void* const* d_in, const int* in_sizes, int n_in,
                              void* d_out, int out_size, void* d_ws, size_t ws_size,
                              hipStream_t stream) {
  const float* x = (const float*)d_in[0];
  const float* w = (const float*)d_in[1];
  const float* gamma = (const float*)d_in[2];
  const float* beta = (const float*)d_in[3];
  const float* mean = (const float*)d_in[4];
  const float* var = (const float*)d_in[5];
  float* out = (float*)d_out;

  const int OUT = in_sizes[2];            // 4096
  const int IN = in_sizes[1] / OUT;       // 4096
  const int B = in_sizes[0] / IN;         // 8192

  int8_t* a8 = (int8_t*)d_ws;
  int8_t* b8 = a8 + (size_t)B * IN;
  float* scale = (float*)(b8 + (size_t)OUT * IN);
  float* bias = scale + OUT;

  const int n16x = B * (IN / 16);
  const int n16w = OUT * (IN / 16);
  pack_sign_i8_kernel<<<(n16x + 255) / 256, 256, 0, stream>>>(
      (const uint4*)x, (uint4*)a8, n16x);
  pack_sign_i8_kernel<<<(n16w + 255) / 256, 256, 0, stream>>>(
      (const uint4*)w, (uint4*)b8, n16w);
  bn_prep_kernel<<<(OUT + 255) / 256, 256, 0, stream>>>(
      gamma, beta, mean, var, scale, bias, OUT);

  dim3 grid((B >> 8) * (OUT >> 8));
  bgemm_i8_p4<<<grid, 512, 0, stream>>>(a8, b8, scale, bias, out, B, OUT, IN);
}

// Round 6
// 177.195 us; speedup vs baseline: 1.0504x; 1.0504x over previous
//
#include <hip/hip_runtime.h>
#include <stdint.h>
#include <stddef.h>

// BinarizeLinearWithFoldedBN on MI355X (gfx950).
// out[b,o] = dot(sign(x[b,:]), sign(w[o,:])) * scale[o] + bias[o]
//   scale = gamma/sqrt(var+eps), bias = beta - mean*scale (exact BN algebra)
// i8 (+1/-1) MFMA GEMM, 256x256 tile, 8 waves, 4-buf slab rotation with
// REGISTER-LEVEL pipelining: ds_reads of phase p+1 issue under MFMAs of
// phase p (sched_barrier-pinned), ONE barrier per 64B slab, counted vmcnt.
// T1 XCD swizzle + T2 granule swizzle (measured 0 conflicts) + T5 setprio.
// Assumes K % 256 == 0 (NT even, >= 8); here K = 4096.

#define BN_EPS 1e-5f
typedef int v4i __attribute__((ext_vector_type(4)));

// ---------------- BN fold ----------------
__global__ void bn_prep_kernel(const float* __restrict__ g, const float* __restrict__ b,
                               const float* __restrict__ m, const float* __restrict__ v,
                               float* __restrict__ scale, float* __restrict__ bias, int n) {
  int i = blockIdx.x * blockDim.x + threadIdx.x;
  if (i >= n) return;
  float s = g[i] * rsqrtf(v[i] + BN_EPS);
  scale[i] = s;
  bias[i] = b[i] - m[i] * s;
}

// ---------------- pack f32 signs -> i8 +1/-1 (16 floats -> 16 bytes per thread) ----
__global__ __launch_bounds__(256) void pack_sign_i8_kernel(
    const uint4* __restrict__ in, uint4* __restrict__ outp, int n16) {
  int t = blockIdx.x * blockDim.x + threadIdx.x;
  if (t >= n16) return;
  const uint4* p = in + (size_t)t * 4;
  uint32_t w[4];
#pragma unroll
  for (int i = 0; i < 4; ++i) {
    uint4 u = p[i];
    uint32_t m = (((uint32_t)((int)u.x >> 31)) & 0xFEu)
               | ((((uint32_t)((int)u.y >> 31)) & 0xFEu) << 8)
               | ((((uint32_t)((int)u.z >> 31)) & 0xFEu) << 16)
               | ((((uint32_t)((int)u.w >> 31)) & 0xFEu) << 24);
    w[i] = 0x01010101u ^ m;
  }
  uint4 o; o.x = w[0]; o.y = w[1]; o.z = w[2]; o.w = w[3];
  outp[t] = o;
}

// ---------------- i8 MFMA GEMM ----------------
// LDS (128 KiB): A slab buf q (q=0..3): q*16384 (256 rows x 64 B)
//                B slab buf q:          65536 + q*16384
// T2 16B-granule XOR swizzle: LDS(row R, chunk C) = global granule C ^ ((R>>1)&3);
//   write: linear gload_lds dest + pre-swizzled SOURCE granule;
//   read: fragment chunk = (lane>>4) ^ ((ln15>>1)&3).  (R4/R5: 0 conflicts.)

#define BAR() asm volatile("s_barrier" ::: "memory")
#define WAITV8() asm volatile("s_waitcnt vmcnt(8)" ::: "memory")
#define WAITV4() asm volatile("s_waitcnt vmcnt(4)" ::: "memory")
#define WAITV0() asm volatile("s_waitcnt vmcnt(0)" ::: "memory")
#define LGKM0() asm volatile("s_waitcnt lgkmcnt(0)" ::: "memory")
#define SCHED0() __builtin_amdgcn_sched_barrier(0)

__global__ __launch_bounds__(512, 2) void bgemm_i8_pipe(
    const int8_t* __restrict__ A8, const int8_t* __restrict__ B8,
    const float* __restrict__ scale, const float* __restrict__ bias,
    float* __restrict__ out, int M, int N, int K) {
  __shared__ __align__(16) int8_t lds[131072];

  const int tid = threadIdx.x;
  const int lane = tid & 63;
  const int wid = tid >> 6;      // 0..7
  const int wm = wid >> 2;       // 0..1  (128-row band)
  const int wn = wid & 3;        // 0..3  (64-col band)

  // T1: bijective XCD swizzle (nwg % 8 == 0 here: 32*16 = 512)
  const int nbx = N >> 8;
  const int nwg = (M >> 8) * nbx;
  const int cpx = nwg >> 3;
  const int bid = (int)blockIdx.x;
  const int swz = (bid & 7) * cpx + (bid >> 3);
  const int row0 = (swz / nbx) << 8;
  const int col0 = (swz % nbx) << 8;

  const int ln15 = lane & 15;
  const int kcs = (((lane >> 4) ^ ((ln15 >> 1) & 3)) << 4);  // T2 read swizzle
  const int arow = wm * 128 + ln15;          // + mh*64 + m*16
  const int brow = wn * 64 + ln15;           // + n*16
  const int srow = wid * 16 + (lane >> 2);   // staging row (2nd inst adds 128)
  const int sch = (((lane & 3) ^ ((lane >> 3) & 3)) << 4);   // T2 write-side source granule
  const int ldw = wid << 10;                 // wave slot in 8KB half-slab

  const size_t rstr = (size_t)128 * K;
  const int8_t* aSt = A8 + (size_t)(row0 + srow) * K + sch;
  const int8_t* bSt = B8 + (size_t)(col0 + srow) * K + sch;

  v4i acc[8][4];
#pragma unroll
  for (int i = 0; i < 8; ++i)
#pragma unroll
    for (int n = 0; n < 4; ++n) { v4i z = {0, 0, 0, 0}; acc[i][n] = z; }

  v4i A[2][8];   // fragment sets (ping/pong): [set][mh*4+m]
  v4i Bf[2][4];  // B fragments per set

#define STAGE(s) do {                                                                 \
  const int bb_ = ((s) & 3) * 16384;                                                  \
  __builtin_amdgcn_global_load_lds(                                                   \
      (const __attribute__((address_space(1))) uint32_t*)(aSt + (size_t)(s) * 64),    \
      (__attribute__((address_space(3))) uint32_t*)(lds + bb_ + ldw), 16, 0, 0);      \
  __builtin_amdgcn_global_load_lds(                                                   \
      (const __attribute__((address_space(1))) uint32_t*)(aSt + rstr + (size_t)(s) * 64), \
      (__attribute__((address_space(3))) uint32_t*)(lds + bb_ + 8192 + ldw), 16, 0, 0); \
  __builtin_amdgcn_global_load_lds(                                                   \
      (const __attribute__((address_space(1))) uint32_t*)(bSt + (size_t)(s) * 64),    \
      (__attribute__((address_space(3))) uint32_t*)(lds + 65536 + bb_ + ldw), 16, 0, 0); \
  __builtin_amdgcn_global_load_lds(                                                   \
      (const __attribute__((address_space(1))) uint32_t*)(bSt + rstr + (size_t)(s) * 64), \
      (__attribute__((address_space(3))) uint32_t*)(lds + 65536 + bb_ + 8192 + ldw), 16, 0, 0); \
} while (0)

#define RD_A4(cs, mh, q) do {                                                         \
  const int8_t* p_ = lds + (q) * 16384 + (arow + (mh) * 64) * 64 + kcs;               \
  A[cs][(mh) * 4 + 0] = *(const v4i*)(p_);                                            \
  A[cs][(mh) * 4 + 1] = *(const v4i*)(p_ + 1024);                                     \
  A[cs][(mh) * 4 + 2] = *(const v4i*)(p_ + 2048);                                     \
  A[cs][(mh) * 4 + 3] = *(const v4i*)(p_ + 3072);                                     \
} while (0)

#define RD_B4(cs, q) do {                                                             \
  const int8_t* p_ = lds + 65536 + (q) * 16384 + brow * 64 + kcs;                     \
  Bf[cs][0] = *(const v4i*)(p_);        Bf[cs][1] = *(const v4i*)(p_ + 1024);         \
  Bf[cs][2] = *(const v4i*)(p_ + 2048); Bf[cs][3] = *(const v4i*)(p_ + 3072);         \
} while (0)

#define MFMA16(mh, cs) do {                                                           \
  __builtin_amdgcn_s_setprio(1);                                                      \
  _Pragma("unroll")                                                                   \
  for (int n_ = 0; n_ < 4; ++n_)                                                      \
    _Pragma("unroll")                                                                 \
    for (int m_ = 0; m_ < 4; ++m_)                                                    \
      acc[(mh) * 4 + m_][n_] = __builtin_amdgcn_mfma_i32_16x16x64_i8(                 \
          A[cs][(mh) * 4 + m_], Bf[cs][n_], acc[(mh) * 4 + m_][n_], 0, 0, 0);         \
  __builtin_amdgcn_s_setprio(0);                                                      \
} while (0)

// one 64B slab: reads of phase p+1 issue before MFMAs of phase p (SCHED0-pinned);
// one barrier per slab; LGKM0 before BAR closes cross-wave read-vs-stage window.
#define SLAB_BODY(t, cs, ns, STG, WV) do {                                            \
  STG;                                                                                \
  RD_A4(cs, 1, (t) & 3);                                                              \
  SCHED0();                                                                           \
  MFMA16(0, cs);                                                                      \
  LGKM0();                                                                            \
  WV;                                                                                 \
  BAR();                                                                              \
  RD_B4(ns, (t + 1) & 3);                                                             \
  RD_A4(ns, 0, (t + 1) & 3);                                                          \
  SCHED0();                                                                           \
  MFMA16(1, cs);                                                                      \
} while (0)

#define SLAB_LAST(t, cs) do {                                                         \
  RD_A4(cs, 1, (t) & 3);                                                              \
  SCHED0();                                                                           \
  MFMA16(0, cs);                                                                      \
  MFMA16(1, cs);                                                                      \
} while (0)

  const int NT = K >> 6;   // 64-byte K-slabs; assumed even, >= 8

  // ---- prologue: prefetch slabs 0,1,2; certify slab 0; preload its mh0/B frags
  STAGE(0); STAGE(1); STAGE(2);
  WAITV8();           // own slab-0 staging loads retired (12 -> 8 outstanding)
  BAR();              // all waves -> slab 0 fully in LDS
  RD_B4(0, 0);
  RD_A4(0, 0, 0);

  // ---- main loop: slab t uses set t&1; stage slab t+3
  int t = 0;
  for (; t + 1 < NT - 3; t += 2) {
    SLAB_BODY(t,     0, 1, STAGE(t + 3), WAITV8());
    SLAB_BODY(t + 1, 1, 0, STAGE(t + 4), WAITV8());
  }
  // NT even -> exactly one leftover fully-staged slab (t == NT-4, set 0)
  SLAB_BODY(NT - 4, 0, 1, STAGE(NT - 1), WAITV8());
  // tail: no staging; drain 8 -> 4 -> 0
  SLAB_BODY(NT - 3, 1, 0, (void)0, WAITV4());
  SLAB_BODY(NT - 2, 0, 1, (void)0, WAITV0());
  SLAB_LAST(NT - 1, 1);

  // ---- epilogue: C/D layout col = lane&15, row = (lane>>4)*4 + reg; acc[i] <-> rows wm*128+i*16
  const int cw = col0 + wn * 64;
  float scv[4], biv[4];
#pragma unroll
  for (int n = 0; n < 4; ++n) {
    int c = cw + n * 16 + ln15;
    scv[n] = scale[c];
    biv[n] = bias[c];
  }
#pragma unroll
  for (int i = 0; i < 8; ++i) {
    const int r0 = row0 + wm * 128 + i * 16 + ((lane >> 4) << 2);
#pragma unroll
    for (int reg = 0; reg < 4; ++reg) {
      float* orow = out + (size_t)(r0 + reg) * N;
#pragma unroll
      for (int n = 0; n < 4; ++n)
        orow[cw + n * 16 + ln15] = fmaf((float)acc[i][n][reg], scv[n], biv[n]);
    }
  }

#undef STAGE
#undef RD_A4
#undef RD_B4
#undef MFMA16
#undef SLAB_BODY
#undef SLAB_LAST
}

// ======================= launch =======================
extern "C" void kernel_launch(void* const* d_in, const int* in_sizes, int n_in,
                              void* d_out, int out_size, void* d_ws, size_t ws_size,
                              hipStream_t stream) {
  const float* x = (const float*)d_in[0];
  const float* w = (const float*)d_in[1];
  const float* gamma = (const float*)d_in[2];
  const float* beta = (const float*)d_in[3];
  const float* mean = (const float*)d_in[4];
  const float* var = (const float*)d_in[5];
  float* out = (float*)d_out;

  const int OUT = in_sizes[2];            // 4096
  const int IN = in_sizes[1] / OUT;       // 4096
  const int B = in_sizes[0] / IN;         // 8192

  int8_t* a8 = (int8_t*)d_ws;
  int8_t* b8 = a8 + (size_t)B * IN;
  float* scale = (float*)(b8 + (size_t)OUT * IN);
  float* bias = scale + OUT;

  const int n16x = B * (IN / 16);
  const int n16w = OUT * (IN / 16);
  pack_sign_i8_kernel<<<(n16x + 255) / 256, 256, 0, stream>>>(
      (const uint4*)x, (uint4*)a8, n16x);
  pack_sign_i8_kernel<<<(n16w + 255) / 256, 256, 0, stream>>>(
      (const uint4*)w, (uint4*)b8, n16w);
  bn_prep_kernel<<<(OUT + 255) / 256, 256, 0, stream>>>(
      gamma, beta, mean, var, scale, bias, OUT);

  dim3 grid((B >> 8) * (OUT >> 8));
  bgemm_i8_pipe<<<grid, 512, 0, stream>>>(a8, b8, scale, bias, out, B, OUT, IN);
}